// Round 12
// baseline (182.110 us; speedup 1.0000x reference)
//
#include <hip/hip_runtime.h>
#include <hip/hip_fp16.h>

#define NG 128
#define CHUNK 4096

__device__ __forceinline__ int wave_iscan(int v, int lane) {
#pragma unroll
  for (int off = 1; off < 64; off <<= 1) {
    int u = __shfl_up(v, off, 64);
    if (lane >= off) v += u;
  }
  return v;
}

// ---- generic scan helpers (for the off array) ---------------------------

__global__ void bsum_kernel(const int* __restrict__ src, int* __restrict__ bsum, int M) {
  __shared__ int wsum[4];
  int tid = threadIdx.x, lane = tid & 63, wid = tid >> 6;
  int i = blockIdx.x * 256 + tid;
  int v = (i < M) ? src[i] : 0;
  int inc = wave_iscan(v, lane);
  if (lane == 63) wsum[wid] = inc;
  __syncthreads();
  if (tid == 0) bsum[blockIdx.x] = wsum[0] + wsum[1] + wsum[2] + wsum[3];
}

__global__ void bscan_kernel(int* __restrict__ bsum, int nb) {
  __shared__ int wsum[16];
  int tid = threadIdx.x, lane = tid & 63, wid = tid >> 6;
  int v = (tid < nb) ? bsum[tid] : 0;
  int inc = wave_iscan(v, lane);
  if (lane == 63) wsum[wid] = inc;
  __syncthreads();
  if (tid == 0) {
    int a = 0;
#pragma unroll
    for (int w = 0; w < 16; ++w) { int t = wsum[w]; wsum[w] = a; a += t; }
  }
  __syncthreads();
  if (tid < nb) bsum[tid] = inc - v + wsum[wid];
}

__global__ void offadd_kernel(int* __restrict__ off, const int* __restrict__ bsum, int M) {
  __shared__ int wsum[4];
  int tid = threadIdx.x, lane = tid & 63, wid = tid >> 6;
  int i = blockIdx.x * 256 + tid;
  int v = (i < M) ? off[i] : 0;
  int inc = wave_iscan(v, lane);
  if (lane == 63) wsum[wid] = inc;
  __syncthreads();
  if (tid == 0) {
    int a = bsum[blockIdx.x];
#pragma unroll
    for (int w = 0; w < 4; ++w) { int t = wsum[w]; wsum[w] = a; a += t; }
  }
  __syncthreads();
  if (i < M) off[i] = inc - v + wsum[wid];
}

// ---- bucketed edge reorder (bucket = dst >> 8) --------------------------

__global__ void hist_kernel(const int* __restrict__ ei, int E, int nblkE, int K,
                            int* __restrict__ off) {
  __shared__ int lh[256];
  int tid = threadIdx.x, blk = blockIdx.x;
  lh[tid] = 0;
  __syncthreads();
  int e0 = blk * CHUNK;
  for (int i = tid; i < CHUNK; i += 256) {
    int e = e0 + i;
    if (e < E) atomicAdd(&lh[ei[E + e] >> 8], 1);
  }
  __syncthreads();
  if (tid < K) off[tid * nblkE + blk] = lh[tid];
}

// partition: epack = (src<<8)|(dst&255) into per-(chunk,bucket) runs
__global__ void part_kernel(const int* __restrict__ ei, int E, int nblkE, int K,
                            const int* __restrict__ off, unsigned int* __restrict__ epack) {
  __shared__ int lcur[256];
  int tid = threadIdx.x, blk = blockIdx.x;
  if (tid < K) lcur[tid] = off[tid * nblkE + blk];
  __syncthreads();
  int e0 = blk * CHUNK;
  for (int i = tid; i < CHUNK; i += 256) {
    int e = e0 + i;
    if (e < E) {
      unsigned int s = (unsigned int)ei[e], d = (unsigned int)ei[E + e];
      int pos = atomicAdd(&lcur[d >> 8], 1);
      epack[pos] = (s << 8) | (d & 255u);
    }
  }
}

// one block per bucket: degree count + scan -> rowptr/deg/dis/xs, esrc fill
__global__ void csr2_kernel(const int* __restrict__ off, int nblkE, int K,
                            const unsigned int* __restrict__ epack,
                            const float* __restrict__ x, int* __restrict__ deg,
                            int* __restrict__ rowptr, float* __restrict__ dis,
                            float* __restrict__ xs, unsigned short* __restrict__ esrc,
                            int N, int E) {
  __shared__ int lcnt[256];
  __shared__ int lcur[256];
  __shared__ int wsum[4];
  int tid = threadIdx.x, b = blockIdx.x;
  int lane = tid & 63, wid = tid >> 6;
  lcnt[tid] = 0;
  __syncthreads();
  int be0 = off[b * nblkE];
  int be1 = (b + 1 < K) ? off[(b + 1) * nblkE] : E;
  for (int i = be0 + tid; i < be1; i += 256) atomicAdd(&lcnt[epack[i] & 255u], 1);
  __syncthreads();
  int v = lcnt[tid];
  int inc = wave_iscan(v, lane);
  if (lane == 63) wsum[wid] = inc;
  __syncthreads();
  if (tid == 0) {
    int a = be0;
#pragma unroll
    for (int w = 0; w < 4; ++w) { int t = wsum[w]; wsum[w] = a; a += t; }
  }
  __syncthreads();
  int exc = inc - v + wsum[wid];
  lcur[tid] = exc;
  int node = (b << 8) + tid;
  if (node < N) {
    rowptr[node] = exc;
    deg[node] = v;
    float di = rsqrtf((float)v + 1.0f);  // +1 self loop
    dis[node] = di;
    float4 xv = ((const float4*)x)[node];
    ((float4*)xs)[node] = make_float4(di * xv.x, di * xv.y, di * xv.z, di * xv.w);
  }
  __syncthreads();
  for (int i = be0 + tid; i < be1; i += 256) {
    unsigned int pk = epack[i];
    int pos = atomicAdd(&lcur[pk & 255u], 1);
    esrc[pos] = (unsigned short)(pk >> 8);
  }
}

// ---- layer 1 fused: wave per node; gather xs; write SLICED fp16 h1p -----
// h1ps[slice][node][8]: slice = lane>>3, elem = lane&7
__global__ void l1_kernel(const int* __restrict__ rowptr, const int* __restrict__ deg,
                          const unsigned short* __restrict__ esrc, const float* __restrict__ xs,
                          const float* __restrict__ x, const float* __restrict__ dis,
                          const float* __restrict__ W1, const float* __restrict__ b1,
                          __half* __restrict__ h1ps, int N) {
  int tid = threadIdx.x;
  int lane = tid & 63, wid = tid >> 6;
  int d = __builtin_amdgcn_readfirstlane(blockIdx.x * 4 + wid);
  if (d >= N) return;
  float di = dis[d];
  int p = __builtin_amdgcn_readfirstlane(rowptr[d]);
  int n = __builtin_amdgcn_readfirstlane(deg[d]);
  float a0 = 0.f, a1 = 0.f, a2 = 0.f, a3 = 0.f;
  for (int k = lane; k < n; k += 64) {
    int e = esrc[p + k];
    float4 v = ((const float4*)xs)[e];
    a0 += v.x; a1 += v.y; a2 += v.z; a3 += v.w;
  }
  if (lane == 0) {  // self loop: + di*x[d]
    float4 xv = ((const float4*)x)[d];
    a0 = fmaf(di, xv.x, a0); a1 = fmaf(di, xv.y, a1);
    a2 = fmaf(di, xv.z, a2); a3 = fmaf(di, xv.w, a3);
  }
#pragma unroll
  for (int off = 1; off < 64; off <<= 1) {
    a0 += __shfl_xor(a0, off, 64);
    a1 += __shfl_xor(a1, off, 64);
    a2 += __shfl_xor(a2, off, 64);
    a3 += __shfl_xor(a3, off, 64);
  }
  a0 *= di; a1 *= di; a2 *= di; a3 *= di;
  float o = b1[lane] + a0 * W1[lane] + a1 * W1[64 + lane] + a2 * W1[128 + lane] + a3 * W1[192 + lane];
  h1ps[(size_t)(lane >> 3) * N * 8 + (size_t)d * 8 + (lane & 7)] =
      __float2half(di * fmaxf(o, 0.0f));
}

// ---- layer 2a: XCD-sliced gather. slice = blockIdx&7 -> XCD via %8 ------
// wave per node; 16 edges/round x 4 lanes/edge (half2 each); v-slice -> vbuf
__global__ void __launch_bounds__(256)
l2a_kernel(const int* __restrict__ rowptr, const int* __restrict__ deg,
           const unsigned short* __restrict__ esrc, const __half* __restrict__ h1ps,
           const float* __restrict__ dis, __half* __restrict__ vbuf, int N) {
  int tid = threadIdx.x;
  int lane = tid & 63, wid = tid >> 6;
  int q = blockIdx.x & 7;
  int d0 = (blockIdx.x >> 3) * 4 + wid;
  if (d0 >= N) return;  // no barriers below: per-wave exit is safe
  int d = __builtin_amdgcn_readfirstlane(d0);
  float di = dis[d];
  const __half* tab = h1ps + (size_t)q * N * 8;
  int p = __builtin_amdgcn_readfirstlane(rowptr[d]);
  int n = __builtin_amdgcn_readfirstlane(deg[d]);
  int fp = lane & 3;  // feature-pair id within slice
  float ax = 0.f, ay = 0.f;
  for (int k = 0; k < n; k += 16) {
    int idx = k + (lane & 15);
    int e_l = esrc[p + ((idx < n) ? idx : (n - 1))];
    int e = __shfl(e_l, lane >> 2, 64);      // edge id for this lane's group
    float m = ((k + (lane >> 2)) < n) ? 1.0f : 0.0f;
    __half2 hv = *(const __half2*)(tab + (size_t)e * 8 + fp * 2);
    float2 f = __half22float2(hv);
    ax = fmaf(m, f.x, ax);
    ay = fmaf(m, f.y, ay);
  }
#pragma unroll
  for (int off = 4; off < 64; off <<= 1) {  // reduce over the 16 edge groups
    ax += __shfl_xor(ax, off, 64);
    ay += __shfl_xor(ay, off, 64);
  }
  float2 sf = __half22float2(*(const __half2*)(tab + (size_t)d * 8 + fp * 2));
  ax = di * (ax + sf.x);  // self loop already dis-scaled in h1ps
  ay = di * (ay + sf.y);
  if (lane < 4) {
    __half2 r;
    r.x = __float2half(ax);
    r.y = __float2half(ay);
    ((__half2*)vbuf)[(size_t)d * 32 + q * 4 + fp] = r;
  }
}

// ---- layer 2b: streaming matmul + relu + run-combined pool --------------
__global__ void __launch_bounds__(256)
l2b_kernel(const __half* __restrict__ vbuf, const float* __restrict__ W2,
           const float* __restrict__ b2, const int* __restrict__ batch,
           float* __restrict__ gsum, int N) {
  __shared__ float vb[4][64];
  __shared__ float obuf[4][64];
  __shared__ int gbuf[4];
  int tid = threadIdx.x;
  int lane = tid & 63, wid = tid >> 6;
  int d0 = blockIdx.x * 4 + wid;
  bool valid = d0 < N;
  int d = __builtin_amdgcn_readfirstlane(valid ? d0 : N - 1);
  float v = __half2float(vbuf[(size_t)d * 64 + lane]);
  vb[wid][lane] = v;  // intra-wave, in-order
  float o = b2[lane];
  const float4* vb4 = (const float4*)vb[wid];
#pragma unroll
  for (int kk = 0; kk < 16; ++kk) {
    float4 vv = vb4[kk];  // uniform address -> broadcast read
    o = fmaf(vv.x, W2[(kk * 4 + 0) * 64 + lane], o);
    o = fmaf(vv.y, W2[(kk * 4 + 1) * 64 + lane], o);
    o = fmaf(vv.z, W2[(kk * 4 + 2) * 64 + lane], o);
    o = fmaf(vv.w, W2[(kk * 4 + 3) * 64 + lane], o);
  }
  obuf[wid][lane] = fmaxf(o, 0.0f);
  if (lane == 0) gbuf[wid] = valid ? batch[d] : -1;
  __syncthreads();
  if (wid == 0) {
    float s = 0.0f;
    int cur = gbuf[0];
#pragma unroll
    for (int r = 0; r < 4; ++r) {
      int g = gbuf[r];
      if (g != cur) {
        if (cur >= 0) atomicAdd(&gsum[cur * 64 + lane], s);
        s = 0.0f;
        cur = g;
      }
      if (g >= 0) s += obuf[r][lane];
    }
    if (cur >= 0) atomicAdd(&gsum[cur * 64 + lane], s);
  }
}

// ---- output: mean via binary search on sorted batch ---------------------

__device__ __forceinline__ int lbound(const int* __restrict__ a, int n, int v) {
  int lo = 0, hi = n;
  while (lo < hi) {
    int mid = (lo + hi) >> 1;
    if (a[mid] < v) lo = mid + 1; else hi = mid;
  }
  return lo;
}

__global__ void out_kernel(const float* __restrict__ gsum, const int* __restrict__ batch,
                           int N, float* __restrict__ out) {
  int t = blockIdx.x * blockDim.x + threadIdx.x;
  if (t >= NG * 64) return;
  int g = t >> 6;
  int cnt = lbound(batch, N, g + 1) - lbound(batch, N, g);
  out[t] = gsum[t] / fmaxf((float)cnt, 1.0f);
}

// ---- launch --------------------------------------------------------------

extern "C" void kernel_launch(void* const* d_in, const int* in_sizes, int n_in,
                              void* d_out, int out_size, void* d_ws, size_t ws_size,
                              hipStream_t stream) {
  const float* x = (const float*)d_in[0];
  const int* ei = (const int*)d_in[1];     // [2,E]: src row then dst row
  const int* batch = (const int*)d_in[2];  // sorted graph ids
  const float* W1 = (const float*)d_in[4];
  const float* b1 = (const float*)d_in[5];
  const float* W2 = (const float*)d_in[6];
  const float* b2 = (const float*)d_in[7];

  const int N = in_sizes[0] / 4;           // 50000 (< 65536: ushort esrc ok)
  const int E = in_sizes[1] / 2;
  const int K = (N + 255) >> 8;                 // buckets (dst>>8)
  const int nblkE = (E + CHUNK - 1) / CHUNK;    // edge chunks
  const int M2 = K * nblkE;
  const int NB2 = (M2 + 255) / 256;             // <= 1024

  // ws layout (4B words unless noted):
  // [gsum 8192] <- zeroed
  // [deg N][rowptr N][xs 4N][dis N][h1ps 64N halves][esrc E ushorts]
  // [off M2][bsum2 1024][overlay: epack E words | vbuf 64N halves]
  float* gsum = (float*)d_ws;
  int* deg = (int*)(gsum + 64 * NG);
  int* rowptr = deg + N;
  float* xs = (float*)(rowptr + N);             // 16B aligned (8192+2N)%4==0
  float* dis = xs + (size_t)4 * N;
  __half* h1ps = (__half*)(dis + N);
  unsigned short* esrc = (unsigned short*)(dis + N + (size_t)32 * N);
  int* off = (int*)(esrc + E);                  // E even -> 4B aligned
  int* bsum2 = off + M2;
  unsigned int* epack = (unsigned int*)(bsum2 + 1024);
  __half* vbuf = (__half*)epack;                // overlay: epack dead after csr2

  hipMemsetAsync(d_ws, 0, (size_t)64 * NG * 4, stream);

  const int B = 256;
  hist_kernel<<<nblkE, 256, 0, stream>>>(ei, E, nblkE, K, off);
  bsum_kernel<<<NB2, 256, 0, stream>>>(off, bsum2, M2);
  bscan_kernel<<<1, 1024, 0, stream>>>(bsum2, NB2);
  offadd_kernel<<<NB2, 256, 0, stream>>>(off, bsum2, M2);
  part_kernel<<<nblkE, 256, 0, stream>>>(ei, E, nblkE, K, off, epack);
  csr2_kernel<<<K, 256, 0, stream>>>(off, nblkE, K, epack, x, deg, rowptr, dis, xs, esrc, N, E);
  l1_kernel<<<(N + 3) / 4, 256, 0, stream>>>(rowptr, deg, esrc, xs, x, dis, W1, b1, h1ps, N);
  l2a_kernel<<<((N + 3) / 4) * 8, 256, 0, stream>>>(rowptr, deg, esrc, h1ps, dis, vbuf, N);
  l2b_kernel<<<(N + 3) / 4, 256, 0, stream>>>(vbuf, W2, b2, batch, gsum, N);
  out_kernel<<<(NG * 64 + B - 1) / B, B, 0, stream>>>(gsum, batch, N, (float*)d_out);
}

// Round 13
// 143.039 us; speedup vs baseline: 1.2731x; 1.2731x over previous
//
#include <hip/hip_runtime.h>
#include <hip/hip_fp16.h>

#define NG 128
#define CHUNK 4096

__device__ __forceinline__ int wave_iscan(int v, int lane) {
#pragma unroll
  for (int off = 1; off < 64; off <<= 1) {
    int u = __shfl_up(v, off, 64);
    if (lane >= off) v += u;
  }
  return v;
}

// ---- generic scan helpers (for the off array) ---------------------------

__global__ void bsum_kernel(const int* __restrict__ src, int* __restrict__ bsum, int M) {
  __shared__ int wsum[4];
  int tid = threadIdx.x, lane = tid & 63, wid = tid >> 6;
  int i = blockIdx.x * 256 + tid;
  int v = (i < M) ? src[i] : 0;
  int inc = wave_iscan(v, lane);
  if (lane == 63) wsum[wid] = inc;
  __syncthreads();
  if (tid == 0) bsum[blockIdx.x] = wsum[0] + wsum[1] + wsum[2] + wsum[3];
}

__global__ void bscan_kernel(int* __restrict__ bsum, int nb) {
  __shared__ int wsum[16];
  int tid = threadIdx.x, lane = tid & 63, wid = tid >> 6;
  int v = (tid < nb) ? bsum[tid] : 0;
  int inc = wave_iscan(v, lane);
  if (lane == 63) wsum[wid] = inc;
  __syncthreads();
  if (tid == 0) {
    int a = 0;
#pragma unroll
    for (int w = 0; w < 16; ++w) { int t = wsum[w]; wsum[w] = a; a += t; }
  }
  __syncthreads();
  if (tid < nb) bsum[tid] = inc - v + wsum[wid];
}

__global__ void offadd_kernel(int* __restrict__ off, const int* __restrict__ bsum, int M) {
  __shared__ int wsum[4];
  int tid = threadIdx.x, lane = tid & 63, wid = tid >> 6;
  int i = blockIdx.x * 256 + tid;
  int v = (i < M) ? off[i] : 0;
  int inc = wave_iscan(v, lane);
  if (lane == 63) wsum[wid] = inc;
  __syncthreads();
  if (tid == 0) {
    int a = bsum[blockIdx.x];
#pragma unroll
    for (int w = 0; w < 4; ++w) { int t = wsum[w]; wsum[w] = a; a += t; }
  }
  __syncthreads();
  if (i < M) off[i] = inc - v + wsum[wid];
}

// ---- bucketed edge reorder (bucket = dst >> 8) --------------------------

__global__ void hist_kernel(const int* __restrict__ ei, int E, int nblkE, int K,
                            int* __restrict__ off) {
  __shared__ int lh[256];
  int tid = threadIdx.x, blk = blockIdx.x;
  lh[tid] = 0;
  __syncthreads();
  int e0 = blk * CHUNK;
  for (int i = tid; i < CHUNK; i += 256) {
    int e = e0 + i;
    if (e < E) atomicAdd(&lh[ei[E + e] >> 8], 1);
  }
  __syncthreads();
  if (tid < K) off[tid * nblkE + blk] = lh[tid];
}

// partition: epack = (src<<8)|(dst&255) into per-(chunk,bucket) runs
__global__ void part_kernel(const int* __restrict__ ei, int E, int nblkE, int K,
                            const int* __restrict__ off, unsigned int* __restrict__ epack) {
  __shared__ int lcur[256];
  int tid = threadIdx.x, blk = blockIdx.x;
  if (tid < K) lcur[tid] = off[tid * nblkE + blk];
  __syncthreads();
  int e0 = blk * CHUNK;
  for (int i = tid; i < CHUNK; i += 256) {
    int e = e0 + i;
    if (e < E) {
      unsigned int s = (unsigned int)ei[e], d = (unsigned int)ei[E + e];
      int pos = atomicAdd(&lcur[d >> 8], 1);
      epack[pos] = (s << 8) | (d & 255u);
    }
  }
}

// one block per bucket: degree count + scan -> rowptr/deg/dis/xs, esrc fill
__global__ void csr2_kernel(const int* __restrict__ off, int nblkE, int K,
                            const unsigned int* __restrict__ epack,
                            const float* __restrict__ x, int* __restrict__ deg,
                            int* __restrict__ rowptr, float* __restrict__ dis,
                            float* __restrict__ xs, unsigned short* __restrict__ esrc,
                            int N, int E) {
  __shared__ int lcnt[256];
  __shared__ int lcur[256];
  __shared__ int wsum[4];
  int tid = threadIdx.x, b = blockIdx.x;
  int lane = tid & 63, wid = tid >> 6;
  lcnt[tid] = 0;
  __syncthreads();
  int be0 = off[b * nblkE];
  int be1 = (b + 1 < K) ? off[(b + 1) * nblkE] : E;
  for (int i = be0 + tid; i < be1; i += 256) atomicAdd(&lcnt[epack[i] & 255u], 1);
  __syncthreads();
  int v = lcnt[tid];
  int inc = wave_iscan(v, lane);
  if (lane == 63) wsum[wid] = inc;
  __syncthreads();
  if (tid == 0) {
    int a = be0;
#pragma unroll
    for (int w = 0; w < 4; ++w) { int t = wsum[w]; wsum[w] = a; a += t; }
  }
  __syncthreads();
  int exc = inc - v + wsum[wid];
  lcur[tid] = exc;
  int node = (b << 8) + tid;
  if (node < N) {
    rowptr[node] = exc;
    deg[node] = v;
    float di = rsqrtf((float)v + 1.0f);  // +1 self loop
    dis[node] = di;
    float4 xv = ((const float4*)x)[node];
    ((float4*)xs)[node] = make_float4(di * xv.x, di * xv.y, di * xv.z, di * xv.w);
  }
  __syncthreads();
  for (int i = be0 + tid; i < be1; i += 256) {
    unsigned int pk = epack[i];
    int pos = atomicAdd(&lcur[pk & 255u], 1);
    esrc[pos] = (unsigned short)(pk >> 8);
  }
}

// ---- layer 1 fused: wave per node; gather xs; int8-quantized h1 table ----
// h1q[d][j] = round(255*o_j/rowmax), scl[d] = rowmax/255, o = dis*relu(a@W1+b1)
__global__ void l1_kernel(const int* __restrict__ rowptr, const int* __restrict__ deg,
                          const unsigned short* __restrict__ esrc, const float* __restrict__ xs,
                          const float* __restrict__ x, const float* __restrict__ dis,
                          const float* __restrict__ W1, const float* __restrict__ b1,
                          unsigned char* __restrict__ h1q, float* __restrict__ scl, int N) {
  int tid = threadIdx.x;
  int lane = tid & 63, wid = tid >> 6;
  int d = __builtin_amdgcn_readfirstlane(blockIdx.x * 4 + wid);
  if (d >= N) return;
  float di = dis[d];
  int p = __builtin_amdgcn_readfirstlane(rowptr[d]);
  int n = __builtin_amdgcn_readfirstlane(deg[d]);
  float a0 = 0.f, a1 = 0.f, a2 = 0.f, a3 = 0.f;
  for (int k = lane; k < n; k += 64) {
    int e = esrc[p + k];
    float4 v = ((const float4*)xs)[e];
    a0 += v.x; a1 += v.y; a2 += v.z; a3 += v.w;
  }
  if (lane == 0) {  // self loop: + di*x[d]
    float4 xv = ((const float4*)x)[d];
    a0 = fmaf(di, xv.x, a0); a1 = fmaf(di, xv.y, a1);
    a2 = fmaf(di, xv.z, a2); a3 = fmaf(di, xv.w, a3);
  }
#pragma unroll
  for (int off = 1; off < 64; off <<= 1) {
    a0 += __shfl_xor(a0, off, 64);
    a1 += __shfl_xor(a1, off, 64);
    a2 += __shfl_xor(a2, off, 64);
    a3 += __shfl_xor(a3, off, 64);
  }
  a0 *= di; a1 *= di; a2 *= di; a3 *= di;
  float o = b1[lane] + a0 * W1[lane] + a1 * W1[64 + lane] + a2 * W1[128 + lane] + a3 * W1[192 + lane];
  o = di * fmaxf(o, 0.0f);
  float rmax = o;
#pragma unroll
  for (int off = 1; off < 64; off <<= 1) rmax = fmaxf(rmax, __shfl_xor(rmax, off, 64));
  float inv = (rmax > 0.0f) ? (255.0f / rmax) : 0.0f;
  h1q[(size_t)d * 64 + lane] = (unsigned char)(int)rintf(o * inv);
  if (lane == 0) scl[d] = (rmax > 0.0f) ? (rmax * (1.0f / 255.0f)) : 1.0f;
}

// ---- layer 2: int8 gather (unroll-16, L2-resident table) + matmul + pool --
__global__ void __launch_bounds__(256)
l2_kernel(const int* __restrict__ rowptr, const int* __restrict__ deg,
          const unsigned short* __restrict__ esrc, const unsigned char* __restrict__ h1q,
          const float* __restrict__ scl, const float* __restrict__ dis,
          const float* __restrict__ W2, const float* __restrict__ b2,
          const int* __restrict__ batch, float* __restrict__ gsum, int N) {
  __shared__ float vbuf[4][64];
  __shared__ float obuf[4][64];
  __shared__ int gbuf[4];
  int tid = threadIdx.x;
  int lane = tid & 63, wid = tid >> 6;
  int d0 = blockIdx.x * 4 + wid;
  bool valid = d0 < N;
  int d = __builtin_amdgcn_readfirstlane(valid ? d0 : N - 1);
  float di = dis[d];
  // self loop: h1q row of d scaled by scl[d]
  float acc0 = scl[d] * (float)h1q[(size_t)d * 64 + lane];
  float acc1 = 0.f, acc2 = 0.f, acc3 = 0.f;
  float acc4 = 0.f, acc5 = 0.f, acc6 = 0.f, acc7 = 0.f;
  int p = __builtin_amdgcn_readfirstlane(rowptr[d]);
  int n = __builtin_amdgcn_readfirstlane(deg[d]);
  for (int k = 0; k < n; k += 16) {
    int es[16];
    float sc[16];
#pragma unroll
    for (int i = 0; i < 16; ++i) {
      int idx = k + i;
      es[i] = esrc[p + ((idx < n) ? idx : (n - 1))];  // uniform scalar loads
      sc[i] = (idx < n) ? scl[es[i]] : 0.0f;          // mask folded into scale
    }
#pragma unroll
    for (int i = 0; i < 16; ++i) {
      float q = (float)h1q[(size_t)es[i] * 64 + lane];
      switch (i & 7) {
        case 0: acc0 = fmaf(sc[i], q, acc0); break;
        case 1: acc1 = fmaf(sc[i], q, acc1); break;
        case 2: acc2 = fmaf(sc[i], q, acc2); break;
        case 3: acc3 = fmaf(sc[i], q, acc3); break;
        case 4: acc4 = fmaf(sc[i], q, acc4); break;
        case 5: acc5 = fmaf(sc[i], q, acc5); break;
        case 6: acc6 = fmaf(sc[i], q, acc6); break;
        case 7: acc7 = fmaf(sc[i], q, acc7); break;
      }
    }
  }
  float v = di * (((acc0 + acc1) + (acc2 + acc3)) + ((acc4 + acc5) + (acc6 + acc7)));
  vbuf[wid][lane] = v;  // intra-wave, in-order
  float o = b2[lane];
  const float4* vb4 = (const float4*)vbuf[wid];
#pragma unroll
  for (int kk = 0; kk < 16; ++kk) {
    float4 vv = vb4[kk];  // uniform address -> broadcast read
    o = fmaf(vv.x, W2[(kk * 4 + 0) * 64 + lane], o);
    o = fmaf(vv.y, W2[(kk * 4 + 1) * 64 + lane], o);
    o = fmaf(vv.z, W2[(kk * 4 + 2) * 64 + lane], o);
    o = fmaf(vv.w, W2[(kk * 4 + 3) * 64 + lane], o);
  }
  obuf[wid][lane] = fmaxf(o, 0.0f);
  if (lane == 0) gbuf[wid] = valid ? batch[d] : -1;
  __syncthreads();
  if (wid == 0) {
    float s = 0.0f;
    int cur = gbuf[0];
#pragma unroll
    for (int r = 0; r < 4; ++r) {
      int g = gbuf[r];
      if (g != cur) {
        if (cur >= 0) atomicAdd(&gsum[cur * 64 + lane], s);
        s = 0.0f;
        cur = g;
      }
      if (g >= 0) s += obuf[r][lane];
    }
    if (cur >= 0) atomicAdd(&gsum[cur * 64 + lane], s);
  }
}

// ---- output: mean via binary search on sorted batch ---------------------

__device__ __forceinline__ int lbound(const int* __restrict__ a, int n, int v) {
  int lo = 0, hi = n;
  while (lo < hi) {
    int mid = (lo + hi) >> 1;
    if (a[mid] < v) lo = mid + 1; else hi = mid;
  }
  return lo;
}

__global__ void out_kernel(const float* __restrict__ gsum, const int* __restrict__ batch,
                           int N, float* __restrict__ out) {
  int t = blockIdx.x * blockDim.x + threadIdx.x;
  if (t >= NG * 64) return;
  int g = t >> 6;
  int cnt = lbound(batch, N, g + 1) - lbound(batch, N, g);
  out[t] = gsum[t] / fmaxf((float)cnt, 1.0f);
}

// ---- launch --------------------------------------------------------------

extern "C" void kernel_launch(void* const* d_in, const int* in_sizes, int n_in,
                              void* d_out, int out_size, void* d_ws, size_t ws_size,
                              hipStream_t stream) {
  const float* x = (const float*)d_in[0];
  const int* ei = (const int*)d_in[1];     // [2,E]: src row then dst row
  const int* batch = (const int*)d_in[2];  // sorted graph ids
  const float* W1 = (const float*)d_in[4];
  const float* b1 = (const float*)d_in[5];
  const float* W2 = (const float*)d_in[6];
  const float* b2 = (const float*)d_in[7];

  const int N = in_sizes[0] / 4;           // 50000 (< 65536: ushort esrc ok)
  const int E = in_sizes[1] / 2;
  const int K = (N + 255) >> 8;                 // buckets (dst>>8)
  const int nblkE = (E + CHUNK - 1) / CHUNK;    // edge chunks
  const int M2 = K * nblkE;
  const int NB2 = (M2 + 255) / 256;             // <= 1024

  // ws layout (4B words unless noted):
  // [gsum 8192] <- zeroed
  // [deg N][rowptr N][xs 4N][dis N][scl N][h1q 64N uchars][esrc E ushorts]
  // [off M2][bsum2 1024][epack E words]
  float* gsum = (float*)d_ws;
  int* deg = (int*)(gsum + 64 * NG);
  int* rowptr = deg + N;
  float* xs = (float*)(rowptr + N);             // (8192+2N)%4==0 -> 16B aligned
  float* dis = xs + (size_t)4 * N;
  float* scl = dis + N;
  unsigned char* h1q = (unsigned char*)(scl + N);
  unsigned short* esrc = (unsigned short*)(h1q + (size_t)64 * N);
  int* off = (int*)(esrc + E);                  // E even -> 4B aligned
  int* bsum2 = off + M2;
  unsigned int* epack = (unsigned int*)(bsum2 + 1024);

  hipMemsetAsync(d_ws, 0, (size_t)64 * NG * 4, stream);

  const int B = 256;
  hist_kernel<<<nblkE, 256, 0, stream>>>(ei, E, nblkE, K, off);
  bsum_kernel<<<NB2, 256, 0, stream>>>(off, bsum2, M2);
  bscan_kernel<<<1, 1024, 0, stream>>>(bsum2, NB2);
  offadd_kernel<<<NB2, 256, 0, stream>>>(off, bsum2, M2);
  part_kernel<<<nblkE, 256, 0, stream>>>(ei, E, nblkE, K, off, epack);
  csr2_kernel<<<K, 256, 0, stream>>>(off, nblkE, K, epack, x, deg, rowptr, dis, xs, esrc, N, E);
  l1_kernel<<<(N + 3) / 4, 256, 0, stream>>>(rowptr, deg, esrc, xs, x, dis, W1, b1, h1q, scl, N);
  l2_kernel<<<(N + 3) / 4, 256, 0, stream>>>(rowptr, deg, esrc, h1q, scl, dis, W2, b2, batch, gsum, N);
  out_kernel<<<(NG * 64 + B - 1) / B, B, 0, stream>>>(gsum, batch, N, (float*)d_out);
}

// Round 14
// 124.929 us; speedup vs baseline: 1.4577x; 1.1450x over previous
//
#include <hip/hip_runtime.h>
#include <hip/hip_fp16.h>

#define NG 128
#define CHUNK 4096

__device__ __forceinline__ int wave_iscan(int v, int lane) {
#pragma unroll
  for (int off = 1; off < 64; off <<= 1) {
    int u = __shfl_up(v, off, 64);
    if (lane >= off) v += u;
  }
  return v;
}

// ---- generic scan helpers (for the off array) ---------------------------

__global__ void bsum_kernel(const int* __restrict__ src, int* __restrict__ bsum, int M) {
  __shared__ int wsum[4];
  int tid = threadIdx.x, lane = tid & 63, wid = tid >> 6;
  int i = blockIdx.x * 256 + tid;
  int v = (i < M) ? src[i] : 0;
  int inc = wave_iscan(v, lane);
  if (lane == 63) wsum[wid] = inc;
  __syncthreads();
  if (tid == 0) bsum[blockIdx.x] = wsum[0] + wsum[1] + wsum[2] + wsum[3];
}

__global__ void bscan_kernel(int* __restrict__ bsum, int nb) {
  __shared__ int wsum[16];
  int tid = threadIdx.x, lane = tid & 63, wid = tid >> 6;
  int v = (tid < nb) ? bsum[tid] : 0;
  int inc = wave_iscan(v, lane);
  if (lane == 63) wsum[wid] = inc;
  __syncthreads();
  if (tid == 0) {
    int a = 0;
#pragma unroll
    for (int w = 0; w < 16; ++w) { int t = wsum[w]; wsum[w] = a; a += t; }
  }
  __syncthreads();
  if (tid < nb) bsum[tid] = inc - v + wsum[wid];
}

__global__ void offadd_kernel(int* __restrict__ off, const int* __restrict__ bsum, int M) {
  __shared__ int wsum[4];
  int tid = threadIdx.x, lane = tid & 63, wid = tid >> 6;
  int i = blockIdx.x * 256 + tid;
  int v = (i < M) ? off[i] : 0;
  int inc = wave_iscan(v, lane);
  if (lane == 63) wsum[wid] = inc;
  __syncthreads();
  if (tid == 0) {
    int a = bsum[blockIdx.x];
#pragma unroll
    for (int w = 0; w < 4; ++w) { int t = wsum[w]; wsum[w] = a; a += t; }
  }
  __syncthreads();
  if (i < M) off[i] = inc - v + wsum[wid];
}

// ---- bucketed edge reorder (bucket = dst >> 8) --------------------------

__global__ void hist_kernel(const int* __restrict__ ei, int E, int nblkE, int K,
                            int* __restrict__ off) {
  __shared__ int lh[256];
  int tid = threadIdx.x, blk = blockIdx.x;
  lh[tid] = 0;
  __syncthreads();
  int e0 = blk * CHUNK;
  for (int i = tid; i < CHUNK; i += 256) {
    int e = e0 + i;
    if (e < E) atomicAdd(&lh[ei[E + e] >> 8], 1);
  }
  __syncthreads();
  if (tid < K) off[tid * nblkE + blk] = lh[tid];
}

// partition: epack = (src<<8)|(dst&255) into per-(chunk,bucket) runs
__global__ void part_kernel(const int* __restrict__ ei, int E, int nblkE, int K,
                            const int* __restrict__ off, unsigned int* __restrict__ epack) {
  __shared__ int lcur[256];
  int tid = threadIdx.x, blk = blockIdx.x;
  if (tid < K) lcur[tid] = off[tid * nblkE + blk];
  __syncthreads();
  int e0 = blk * CHUNK;
  for (int i = tid; i < CHUNK; i += 256) {
    int e = e0 + i;
    if (e < E) {
      unsigned int s = (unsigned int)ei[e], d = (unsigned int)ei[E + e];
      int pos = atomicAdd(&lcur[d >> 8], 1);
      epack[pos] = (s << 8) | (d & 255u);
    }
  }
}

// one block per bucket: degree count + scan -> rowptr/deg/dis/xs, esrc fill
__global__ void csr2_kernel(const int* __restrict__ off, int nblkE, int K,
                            const unsigned int* __restrict__ epack,
                            const float* __restrict__ x, int* __restrict__ deg,
                            int* __restrict__ rowptr, float* __restrict__ dis,
                            float* __restrict__ xs, unsigned short* __restrict__ esrc,
                            int N, int E) {
  __shared__ int lcnt[256];
  __shared__ int lcur[256];
  __shared__ int wsum[4];
  int tid = threadIdx.x, b = blockIdx.x;
  int lane = tid & 63, wid = tid >> 6;
  lcnt[tid] = 0;
  __syncthreads();
  int be0 = off[b * nblkE];
  int be1 = (b + 1 < K) ? off[(b + 1) * nblkE] : E;
  for (int i = be0 + tid; i < be1; i += 256) atomicAdd(&lcnt[epack[i] & 255u], 1);
  __syncthreads();
  int v = lcnt[tid];
  int inc = wave_iscan(v, lane);
  if (lane == 63) wsum[wid] = inc;
  __syncthreads();
  if (tid == 0) {
    int a = be0;
#pragma unroll
    for (int w = 0; w < 4; ++w) { int t = wsum[w]; wsum[w] = a; a += t; }
  }
  __syncthreads();
  int exc = inc - v + wsum[wid];
  lcur[tid] = exc;
  int node = (b << 8) + tid;
  if (node < N) {
    rowptr[node] = exc;
    deg[node] = v;
    float di = rsqrtf((float)v + 1.0f);  // +1 self loop
    dis[node] = di;
    float4 xv = ((const float4*)x)[node];
    ((float4*)xs)[node] = make_float4(di * xv.x, di * xv.y, di * xv.z, di * xv.w);
  }
  __syncthreads();
  for (int i = be0 + tid; i < be1; i += 256) {
    unsigned int pk = epack[i];
    int pos = atomicAdd(&lcur[pk & 255u], 1);
    esrc[pos] = (unsigned short)(pk >> 8);
  }
}

// ---- layer 1 fused: wave per node; gather xs; h1p = fp16(dis*relu(a@W1+b1))
__global__ void l1_kernel(const int* __restrict__ rowptr, const int* __restrict__ deg,
                          const unsigned short* __restrict__ esrc, const float* __restrict__ xs,
                          const float* __restrict__ x, const float* __restrict__ dis,
                          const float* __restrict__ W1, const float* __restrict__ b1,
                          __half* __restrict__ h1p, int N) {
  int tid = threadIdx.x;
  int lane = tid & 63, wid = tid >> 6;
  int d = __builtin_amdgcn_readfirstlane(blockIdx.x * 4 + wid);
  if (d >= N) return;
  float di = dis[d];
  int p = __builtin_amdgcn_readfirstlane(rowptr[d]);
  int n = __builtin_amdgcn_readfirstlane(deg[d]);
  float a0 = 0.f, a1 = 0.f, a2 = 0.f, a3 = 0.f;
  for (int k = lane; k < n; k += 64) {
    int e = esrc[p + k];
    float4 v = ((const float4*)xs)[e];
    a0 += v.x; a1 += v.y; a2 += v.z; a3 += v.w;
  }
  if (lane == 0) {  // self loop: + di*x[d]
    float4 xv = ((const float4*)x)[d];
    a0 = fmaf(di, xv.x, a0); a1 = fmaf(di, xv.y, a1);
    a2 = fmaf(di, xv.z, a2); a3 = fmaf(di, xv.w, a3);
  }
#pragma unroll
  for (int off = 1; off < 64; off <<= 1) {
    a0 += __shfl_xor(a0, off, 64);
    a1 += __shfl_xor(a1, off, 64);
    a2 += __shfl_xor(a2, off, 64);
    a3 += __shfl_xor(a3, off, 64);
  }
  a0 *= di; a1 *= di; a2 *= di; a3 *= di;
  float o = b1[lane] + a0 * W1[lane] + a1 * W1[64 + lane] + a2 * W1[128 + lane] + a3 * W1[192 + lane];
  h1p[(size_t)d * 64 + lane] = __float2half(di * fmaxf(o, 0.0f));
}

// ---- layer 2: fp16 gather, hoisted 32-edge block (2-epoch chain) --------
__global__ void __launch_bounds__(256)
l2_kernel(const int* __restrict__ rowptr, const int* __restrict__ deg,
          const unsigned short* __restrict__ esrc, const __half* __restrict__ h1p,
          const float* __restrict__ dis, const float* __restrict__ W2,
          const float* __restrict__ b2, const int* __restrict__ batch,
          float* __restrict__ gsum, int N) {
  __shared__ float vbuf[4][64];
  __shared__ float obuf[4][64];
  __shared__ int gbuf[4];
  int tid = threadIdx.x;
  int lane = tid & 63, wid = tid >> 6;
  int d0 = blockIdx.x * 4 + wid;
  bool valid = d0 < N;
  int d = __builtin_amdgcn_readfirstlane(valid ? d0 : N - 1);
  float di = dis[d];
  float acc0 = __half2float(h1p[(size_t)d * 64 + lane]);  // self loop
  float acc1 = 0.f, acc2 = 0.f, acc3 = 0.f;
  float acc4 = 0.f, acc5 = 0.f, acc6 = 0.f, acc7 = 0.f;
  int p = __builtin_amdgcn_readfirstlane(rowptr[d]);
  int n = __builtin_amdgcn_readfirstlane(deg[d]);
  for (int k = 0; k < n; k += 32) {
    // epoch 1: 32 uniform index loads (independent, all in flight)
    int es[32];
#pragma unroll
    for (int i = 0; i < 32; ++i) {
      int idx = k + i;
      es[i] = esrc[p + ((idx < n) ? idx : (n - 1))];
    }
    // epoch 2: 32 independent row-gathers, FMA with mask
#pragma unroll
    for (int i = 0; i < 32; ++i) {
      float m = (k + i < n) ? 1.0f : 0.0f;
      float v = __half2float(h1p[(size_t)es[i] * 64 + lane]);
      switch (i & 7) {
        case 0: acc0 = fmaf(m, v, acc0); break;
        case 1: acc1 = fmaf(m, v, acc1); break;
        case 2: acc2 = fmaf(m, v, acc2); break;
        case 3: acc3 = fmaf(m, v, acc3); break;
        case 4: acc4 = fmaf(m, v, acc4); break;
        case 5: acc5 = fmaf(m, v, acc5); break;
        case 6: acc6 = fmaf(m, v, acc6); break;
        case 7: acc7 = fmaf(m, v, acc7); break;
      }
    }
  }
  float v = di * (((acc0 + acc1) + (acc2 + acc3)) + ((acc4 + acc5) + (acc6 + acc7)));
  vbuf[wid][lane] = v;  // intra-wave, in-order
  float o = b2[lane];
  const float4* vb4 = (const float4*)vbuf[wid];
#pragma unroll
  for (int kk = 0; kk < 16; ++kk) {
    float4 vv = vb4[kk];  // uniform address -> broadcast read
    o = fmaf(vv.x, W2[(kk * 4 + 0) * 64 + lane], o);
    o = fmaf(vv.y, W2[(kk * 4 + 1) * 64 + lane], o);
    o = fmaf(vv.z, W2[(kk * 4 + 2) * 64 + lane], o);
    o = fmaf(vv.w, W2[(kk * 4 + 3) * 64 + lane], o);
  }
  obuf[wid][lane] = fmaxf(o, 0.0f);
  if (lane == 0) gbuf[wid] = valid ? batch[d] : -1;
  __syncthreads();
  if (wid == 0) {
    float s = 0.0f;
    int cur = gbuf[0];
#pragma unroll
    for (int r = 0; r < 4; ++r) {
      int g = gbuf[r];
      if (g != cur) {
        if (cur >= 0) atomicAdd(&gsum[cur * 64 + lane], s);
        s = 0.0f;
        cur = g;
      }
      if (g >= 0) s += obuf[r][lane];
    }
    if (cur >= 0) atomicAdd(&gsum[cur * 64 + lane], s);
  }
}

// ---- output: mean via binary search on sorted batch ---------------------

__device__ __forceinline__ int lbound(const int* __restrict__ a, int n, int v) {
  int lo = 0, hi = n;
  while (lo < hi) {
    int mid = (lo + hi) >> 1;
    if (a[mid] < v) lo = mid + 1; else hi = mid;
  }
  return lo;
}

__global__ void out_kernel(const float* __restrict__ gsum, const int* __restrict__ batch,
                           int N, float* __restrict__ out) {
  int t = blockIdx.x * blockDim.x + threadIdx.x;
  if (t >= NG * 64) return;
  int g = t >> 6;
  int cnt = lbound(batch, N, g + 1) - lbound(batch, N, g);
  out[t] = gsum[t] / fmaxf((float)cnt, 1.0f);
}

// ---- launch --------------------------------------------------------------

extern "C" void kernel_launch(void* const* d_in, const int* in_sizes, int n_in,
                              void* d_out, int out_size, void* d_ws, size_t ws_size,
                              hipStream_t stream) {
  const float* x = (const float*)d_in[0];
  const int* ei = (const int*)d_in[1];     // [2,E]: src row then dst row
  const int* batch = (const int*)d_in[2];  // sorted graph ids
  const float* W1 = (const float*)d_in[4];
  const float* b1 = (const float*)d_in[5];
  const float* W2 = (const float*)d_in[6];
  const float* b2 = (const float*)d_in[7];

  const int N = in_sizes[0] / 4;           // 50000 (< 65536: ushort esrc ok)
  const int E = in_sizes[1] / 2;
  const int K = (N + 255) >> 8;                 // buckets (dst>>8)
  const int nblkE = (E + CHUNK - 1) / CHUNK;    // edge chunks
  const int M2 = K * nblkE;
  const int NB2 = (M2 + 255) / 256;             // <= 1024

  // ws layout (4B words unless noted):
  // [gsum 8192] <- zeroed
  // [deg N][rowptr N][xs 4N][dis N][h1p 64N halves][esrc E ushorts]
  // [off M2][bsum2 1024][epack E words]
  float* gsum = (float*)d_ws;
  int* deg = (int*)(gsum + 64 * NG);
  int* rowptr = deg + N;
  float* xs = (float*)(rowptr + N);             // (8192+2N)%4==0 -> 16B aligned
  float* dis = xs + (size_t)4 * N;
  __half* h1p = (__half*)(dis + N);
  unsigned short* esrc = (unsigned short*)(dis + N + (size_t)32 * N);
  int* off = (int*)(esrc + E);                  // E even -> 4B aligned
  int* bsum2 = off + M2;
  unsigned int* epack = (unsigned int*)(bsum2 + 1024);

  hipMemsetAsync(d_ws, 0, (size_t)64 * NG * 4, stream);

  const int B = 256;
  hist_kernel<<<nblkE, 256, 0, stream>>>(ei, E, nblkE, K, off);
  bsum_kernel<<<NB2, 256, 0, stream>>>(off, bsum2, M2);
  bscan_kernel<<<1, 1024, 0, stream>>>(bsum2, NB2);
  offadd_kernel<<<NB2, 256, 0, stream>>>(off, bsum2, M2);
  part_kernel<<<nblkE, 256, 0, stream>>>(ei, E, nblkE, K, off, epack);
  csr2_kernel<<<K, 256, 0, stream>>>(off, nblkE, K, epack, x, deg, rowptr, dis, xs, esrc, N, E);
  l1_kernel<<<(N + 3) / 4, 256, 0, stream>>>(rowptr, deg, esrc, xs, x, dis, W1, b1, h1p, N);
  l2_kernel<<<(N + 3) / 4, 256, 0, stream>>>(rowptr, deg, esrc, h1p, dis, W2, b2, batch, gsum, N);
  out_kernel<<<(NG * 64 + B - 1) / B, B, 0, stream>>>(gsum, batch, N, (float*)d_out);
}

// Round 15
// 110.837 us; speedup vs baseline: 1.6430x; 1.1271x over previous
//
#include <hip/hip_runtime.h>
#include <hip/hip_fp16.h>

#define NG 128
#define CHUNK 4096

__device__ __forceinline__ int wave_iscan(int v, int lane) {
#pragma unroll
  for (int off = 1; off < 64; off <<= 1) {
    int u = __shfl_up(v, off, 64);
    if (lane >= off) v += u;
  }
  return v;
}

// ---- generic scan helpers (for the off array) ---------------------------

__global__ void bsum_kernel(const int* __restrict__ src, int* __restrict__ bsum, int M) {
  __shared__ int wsum[4];
  int tid = threadIdx.x, lane = tid & 63, wid = tid >> 6;
  int i = blockIdx.x * 256 + tid;
  int v = (i < M) ? src[i] : 0;
  int inc = wave_iscan(v, lane);
  if (lane == 63) wsum[wid] = inc;
  __syncthreads();
  if (tid == 0) bsum[blockIdx.x] = wsum[0] + wsum[1] + wsum[2] + wsum[3];
}

__global__ void bscan_kernel(int* __restrict__ bsum, int nb) {
  __shared__ int wsum[16];
  int tid = threadIdx.x, lane = tid & 63, wid = tid >> 6;
  int v = (tid < nb) ? bsum[tid] : 0;
  int inc = wave_iscan(v, lane);
  if (lane == 63) wsum[wid] = inc;
  __syncthreads();
  if (tid == 0) {
    int a = 0;
#pragma unroll
    for (int w = 0; w < 16; ++w) { int t = wsum[w]; wsum[w] = a; a += t; }
  }
  __syncthreads();
  if (tid < nb) bsum[tid] = inc - v + wsum[wid];
}

__global__ void offadd_kernel(int* __restrict__ off, const int* __restrict__ bsum, int M) {
  __shared__ int wsum[4];
  int tid = threadIdx.x, lane = tid & 63, wid = tid >> 6;
  int i = blockIdx.x * 256 + tid;
  int v = (i < M) ? off[i] : 0;
  int inc = wave_iscan(v, lane);
  if (lane == 63) wsum[wid] = inc;
  __syncthreads();
  if (tid == 0) {
    int a = bsum[blockIdx.x];
#pragma unroll
    for (int w = 0; w < 4; ++w) { int t = wsum[w]; wsum[w] = a; a += t; }
  }
  __syncthreads();
  if (i < M) off[i] = inc - v + wsum[wid];
}

// ---- bucketed edge reorder (bucket = dst >> 8) --------------------------

__global__ void hist_kernel(const int* __restrict__ ei, int E, int nblkE, int K,
                            int* __restrict__ off) {
  __shared__ int lh[256];
  int tid = threadIdx.x, blk = blockIdx.x;
  lh[tid] = 0;
  __syncthreads();
  int e0 = blk * CHUNK;
  for (int i = tid; i < CHUNK; i += 256) {
    int e = e0 + i;
    if (e < E) atomicAdd(&lh[ei[E + e] >> 8], 1);
  }
  __syncthreads();
  if (tid < K) off[tid * nblkE + blk] = lh[tid];
}

// partition: epack = (src<<8)|(dst&255) into per-(chunk,bucket) runs
__global__ void part_kernel(const int* __restrict__ ei, int E, int nblkE, int K,
                            const int* __restrict__ off, unsigned int* __restrict__ epack) {
  __shared__ int lcur[256];
  int tid = threadIdx.x, blk = blockIdx.x;
  if (tid < K) lcur[tid] = off[tid * nblkE + blk];
  __syncthreads();
  int e0 = blk * CHUNK;
  for (int i = tid; i < CHUNK; i += 256) {
    int e = e0 + i;
    if (e < E) {
      unsigned int s = (unsigned int)ei[e], d = (unsigned int)ei[E + e];
      int pos = atomicAdd(&lcur[d >> 8], 1);
      epack[pos] = (s << 8) | (d & 255u);
    }
  }
}

// one block per bucket: degree count + scan -> rowptr/deg/dis/xs, esrc fill
__global__ void csr2_kernel(const int* __restrict__ off, int nblkE, int K,
                            const unsigned int* __restrict__ epack,
                            const float* __restrict__ x, int* __restrict__ deg,
                            int* __restrict__ rowptr, float* __restrict__ dis,
                            float* __restrict__ xs, unsigned short* __restrict__ esrc,
                            int N, int E) {
  __shared__ int lcnt[256];
  __shared__ int lcur[256];
  __shared__ int wsum[4];
  int tid = threadIdx.x, b = blockIdx.x;
  int lane = tid & 63, wid = tid >> 6;
  lcnt[tid] = 0;
  __syncthreads();
  int be0 = off[b * nblkE];
  int be1 = (b + 1 < K) ? off[(b + 1) * nblkE] : E;
  for (int i = be0 + tid; i < be1; i += 256) atomicAdd(&lcnt[epack[i] & 255u], 1);
  __syncthreads();
  int v = lcnt[tid];
  int inc = wave_iscan(v, lane);
  if (lane == 63) wsum[wid] = inc;
  __syncthreads();
  if (tid == 0) {
    int a = be0;
#pragma unroll
    for (int w = 0; w < 4; ++w) { int t = wsum[w]; wsum[w] = a; a += t; }
  }
  __syncthreads();
  int exc = inc - v + wsum[wid];
  lcur[tid] = exc;
  int node = (b << 8) + tid;
  if (node < N) {
    rowptr[node] = exc;
    deg[node] = v;
    float di = rsqrtf((float)v + 1.0f);  // +1 self loop
    dis[node] = di;
    float4 xv = ((const float4*)x)[node];
    ((float4*)xs)[node] = make_float4(di * xv.x, di * xv.y, di * xv.z, di * xv.w);
  }
  __syncthreads();
  for (int i = be0 + tid; i < be1; i += 256) {
    unsigned int pk = epack[i];
    int pos = atomicAdd(&lcur[pk & 255u], 1);
    esrc[pos] = (unsigned short)(pk >> 8);
  }
}

// ---- layer 1 fused: wave per node; gather xs; h1p = fp16(dis*relu(a@W1+b1))
__global__ void l1_kernel(const int* __restrict__ rowptr, const int* __restrict__ deg,
                          const unsigned short* __restrict__ esrc, const float* __restrict__ xs,
                          const float* __restrict__ x, const float* __restrict__ dis,
                          const float* __restrict__ W1, const float* __restrict__ b1,
                          __half* __restrict__ h1p, int N) {
  int tid = threadIdx.x;
  int lane = tid & 63, wid = tid >> 6;
  int d = __builtin_amdgcn_readfirstlane(blockIdx.x * 4 + wid);
  if (d >= N) return;
  float di = dis[d];
  int p = __builtin_amdgcn_readfirstlane(rowptr[d]);
  int n = __builtin_amdgcn_readfirstlane(deg[d]);
  float a0 = 0.f, a1 = 0.f, a2 = 0.f, a3 = 0.f;
  for (int k = lane; k < n; k += 64) {
    int e = esrc[p + k];
    float4 v = ((const float4*)xs)[e];
    a0 += v.x; a1 += v.y; a2 += v.z; a3 += v.w;
  }
  if (lane == 0) {  // self loop: + di*x[d]
    float4 xv = ((const float4*)x)[d];
    a0 = fmaf(di, xv.x, a0); a1 = fmaf(di, xv.y, a1);
    a2 = fmaf(di, xv.z, a2); a3 = fmaf(di, xv.w, a3);
  }
#pragma unroll
  for (int off = 1; off < 64; off <<= 1) {
    a0 += __shfl_xor(a0, off, 64);
    a1 += __shfl_xor(a1, off, 64);
    a2 += __shfl_xor(a2, off, 64);
    a3 += __shfl_xor(a3, off, 64);
  }
  a0 *= di; a1 *= di; a2 *= di; a3 *= di;
  float o = b1[lane] + a0 * W1[lane] + a1 * W1[64 + lane] + a2 * W1[128 + lane] + a3 * W1[192 + lane];
  h1p[(size_t)d * 64 + lane] = __float2half(di * fmaxf(o, 0.0f));
}

// ---- layer 2: LDS-staged indices + fp16 gather (unroll-16) + matmul + pool
__global__ void __launch_bounds__(256)
l2_kernel(const int* __restrict__ rowptr, const int* __restrict__ deg,
          const unsigned short* __restrict__ esrc, const __half* __restrict__ h1p,
          const float* __restrict__ dis, const float* __restrict__ W2,
          const float* __restrict__ b2, const int* __restrict__ batch,
          float* __restrict__ gsum, int N) {
  __shared__ __align__(16) unsigned short ebuf[4][64];
  __shared__ float vbuf[4][64];
  __shared__ float obuf[4][64];
  __shared__ int gbuf[4];
  int tid = threadIdx.x;
  int lane = tid & 63, wid = tid >> 6;
  int d0 = blockIdx.x * 4 + wid;
  bool valid = d0 < N;
  int d = __builtin_amdgcn_readfirstlane(valid ? d0 : N - 1);
  float di = dis[d];
  float acc0 = __half2float(h1p[(size_t)d * 64 + lane]);  // self loop
  float acc1 = 0.f, acc2 = 0.f, acc3 = 0.f;
  float acc4 = 0.f, acc5 = 0.f, acc6 = 0.f, acc7 = 0.f;
  int p = __builtin_amdgcn_readfirstlane(rowptr[d]);
  int n = __builtin_amdgcn_readfirstlane(deg[d]);
  for (int base = 0; base < n; base += 64) {
    int m64 = n - base;
    if (m64 > 64) m64 = 64;
    // one coalesced VMEM: this wave's next <=64 edge indices -> LDS (clamped)
    ebuf[wid][lane] = esrc[p + base + ((lane < m64) ? lane : (m64 - 1))];
    // intra-wave ds_write -> ds_read ordering handled by compiler lgkmcnt
    for (int k = 0; k < m64; k += 16) {
      uint4 wA = *(const uint4*)&ebuf[wid][k];      // 8 packed indices
      uint4 wB = *(const uint4*)&ebuf[wid][k + 8];  // 8 more (clamped tail safe)
      unsigned int ua0 = wA.x, ua1 = wA.y, ua2 = wA.z, ua3 = wA.w;
      unsigned int ub0 = wB.x, ub1 = wB.y, ub2 = wB.z, ub3 = wB.w;
#pragma unroll
      for (int i = 0; i < 8; ++i) {
        unsigned int u = (i == 0) ? ua0 : (i == 1) ? ua1 : (i == 2) ? ua2 : (i == 3) ? ua3
                       : (i == 4) ? ub0 : (i == 5) ? ub1 : (i == 6) ? ub2 : ub3;
        int ea = (int)(u & 0xffffu), eb = (int)(u >> 16);
        float ma = (k + 2 * i < m64) ? 1.0f : 0.0f;
        float mb = (k + 2 * i + 1 < m64) ? 1.0f : 0.0f;
        float va = __half2float(h1p[(size_t)ea * 64 + lane]);
        float vb = __half2float(h1p[(size_t)eb * 64 + lane]);
        switch (i & 3) {
          case 0: acc0 = fmaf(ma, va, acc0); acc1 = fmaf(mb, vb, acc1); break;
          case 1: acc2 = fmaf(ma, va, acc2); acc3 = fmaf(mb, vb, acc3); break;
          case 2: acc4 = fmaf(ma, va, acc4); acc5 = fmaf(mb, vb, acc5); break;
          case 3: acc6 = fmaf(ma, va, acc6); acc7 = fmaf(mb, vb, acc7); break;
        }
      }
    }
  }
  float v = di * (((acc0 + acc1) + (acc2 + acc3)) + ((acc4 + acc5) + (acc6 + acc7)));
  vbuf[wid][lane] = v;  // intra-wave, in-order
  float o = b2[lane];
  const float4* vb4 = (const float4*)vbuf[wid];
#pragma unroll
  for (int kk = 0; kk < 16; ++kk) {
    float4 vv = vb4[kk];  // uniform address -> broadcast read
    o = fmaf(vv.x, W2[(kk * 4 + 0) * 64 + lane], o);
    o = fmaf(vv.y, W2[(kk * 4 + 1) * 64 + lane], o);
    o = fmaf(vv.z, W2[(kk * 4 + 2) * 64 + lane], o);
    o = fmaf(vv.w, W2[(kk * 4 + 3) * 64 + lane], o);
  }
  obuf[wid][lane] = fmaxf(o, 0.0f);
  if (lane == 0) gbuf[wid] = valid ? batch[d] : -1;
  __syncthreads();
  if (wid == 0) {
    float s = 0.0f;
    int cur = gbuf[0];
#pragma unroll
    for (int r = 0; r < 4; ++r) {
      int g = gbuf[r];
      if (g != cur) {
        if (cur >= 0) atomicAdd(&gsum[cur * 64 + lane], s);
        s = 0.0f;
        cur = g;
      }
      if (g >= 0) s += obuf[r][lane];
    }
    if (cur >= 0) atomicAdd(&gsum[cur * 64 + lane], s);
  }
}

// ---- output: mean via binary search on sorted batch ---------------------

__device__ __forceinline__ int lbound(const int* __restrict__ a, int n, int v) {
  int lo = 0, hi = n;
  while (lo < hi) {
    int mid = (lo + hi) >> 1;
    if (a[mid] < v) lo = mid + 1; else hi = mid;
  }
  return lo;
}

__global__ void out_kernel(const float* __restrict__ gsum, const int* __restrict__ batch,
                           int N, float* __restrict__ out) {
  int t = blockIdx.x * blockDim.x + threadIdx.x;
  if (t >= NG * 64) return;
  int g = t >> 6;
  int cnt = lbound(batch, N, g + 1) - lbound(batch, N, g);
  out[t] = gsum[t] / fmaxf((float)cnt, 1.0f);
}

// ---- launch --------------------------------------------------------------

extern "C" void kernel_launch(void* const* d_in, const int* in_sizes, int n_in,
                              void* d_out, int out_size, void* d_ws, size_t ws_size,
                              hipStream_t stream) {
  const float* x = (const float*)d_in[0];
  const int* ei = (const int*)d_in[1];     // [2,E]: src row then dst row
  const int* batch = (const int*)d_in[2];  // sorted graph ids
  const float* W1 = (const float*)d_in[4];
  const float* b1 = (const float*)d_in[5];
  const float* W2 = (const float*)d_in[6];
  const float* b2 = (const float*)d_in[7];

  const int N = in_sizes[0] / 4;           // 50000 (< 65536: ushort esrc ok)
  const int E = in_sizes[1] / 2;
  const int K = (N + 255) >> 8;                 // buckets (dst>>8)
  const int nblkE = (E + CHUNK - 1) / CHUNK;    // edge chunks
  const int M2 = K * nblkE;
  const int NB2 = (M2 + 255) / 256;             // <= 1024

  // ws layout (4B words unless noted):
  // [gsum 8192] <- zeroed
  // [deg N][rowptr N][xs 4N][dis N][h1p 64N halves][esrc E ushorts]
  // [off M2][bsum2 1024][epack E words]
  float* gsum = (float*)d_ws;
  int* deg = (int*)(gsum + 64 * NG);
  int* rowptr = deg + N;
  float* xs = (float*)(rowptr + N);             // (8192+2N)%4==0 -> 16B aligned
  float* dis = xs + (size_t)4 * N;
  __half* h1p = (__half*)(dis + N);
  unsigned short* esrc = (unsigned short*)(dis + N + (size_t)32 * N);
  int* off = (int*)(esrc + E);                  // E even -> 4B aligned
  int* bsum2 = off + M2;
  unsigned int* epack = (unsigned int*)(bsum2 + 1024);

  hipMemsetAsync(d_ws, 0, (size_t)64 * NG * 4, stream);

  const int B = 256;
  hist_kernel<<<nblkE, 256, 0, stream>>>(ei, E, nblkE, K, off);
  bsum_kernel<<<NB2, 256, 0, stream>>>(off, bsum2, M2);
  bscan_kernel<<<1, 1024, 0, stream>>>(bsum2, NB2);
  offadd_kernel<<<NB2, 256, 0, stream>>>(off, bsum2, M2);
  part_kernel<<<nblkE, 256, 0, stream>>>(ei, E, nblkE, K, off, epack);
  csr2_kernel<<<K, 256, 0, stream>>>(off, nblkE, K, epack, x, deg, rowptr, dis, xs, esrc, N, E);
  l1_kernel<<<(N + 3) / 4, 256, 0, stream>>>(rowptr, deg, esrc, xs, x, dis, W1, b1, h1p, N);
  l2_kernel<<<(N + 3) / 4, 256, 0, stream>>>(rowptr, deg, esrc, h1p, dis, W2, b2, batch, gsum, N);
  out_kernel<<<(NG * 64 + B - 1) / B, B, 0, stream>>>(gsum, batch, N, (float*)d_out);
}